// Round 1
// baseline (407.975 us; speedup 1.0000x reference)
//
#include <hip/hip_runtime.h>
#include <stdint.h>

// ---------------------------------------------------------------------------
// Equivariant conv: out = self_connection + conv3d(x, K(tp_weight)), fused as
// a single sparse-tap implicit-GEMM bf16 MFMA conv (sc folded into center tap).
// ---------------------------------------------------------------------------

#define NT_REAL 179   // taps with d^2 <= 12 (radial shells vanish beyond r=3.5)
#define NT_PAD  180   // padded to multiple of 4 (4 taps per MFMA k=32)
#define NGRP    45    // NT_PAD/4

typedef short s16x8 __attribute__((ext_vector_type(8)));
typedef float f32x4 __attribute__((ext_vector_type(4)));

struct Taps {
  int n;
  short dlin[NT_PAD];                       // (dz*14+dy)*14+dx  (halo linear offset)
  unsigned char dz[NT_PAD], dy[NT_PAD], dx[NT_PAD];
};
constexpr Taps mk_taps() {
  Taps t{};
  t.n = 0;
  for (int a = 0; a < 7; ++a)
    for (int b = 0; b < 7; ++b)
      for (int c = 0; c < 7; ++c) {
        int d2 = (a-3)*(a-3) + (b-3)*(b-3) + (c-3)*(c-3);
        if (d2 <= 12) {
          t.dz[t.n] = (unsigned char)a; t.dy[t.n] = (unsigned char)b;
          t.dx[t.n] = (unsigned char)c;
          t.dlin[t.n] = (short)((a*14 + b)*14 + c);
          ++t.n;
        }
      }
  for (int i = t.n; i < NT_PAD; ++i) {      // pad tap: zero weights, valid addr
    t.dz[i] = 3; t.dy[i] = 3; t.dx[i] = 3; t.dlin[i] = t.dlin[0];
  }
  return t;
}
__device__ constexpr Taps TAPS = mk_taps();
static_assert(mk_taps().n == NT_REAL, "tap count");

static __device__ inline unsigned short f2bf(float f) {   // RNE fp32->bf16
  unsigned int u = __float_as_uint(f);
  unsigned int r = u + 0x7FFFu + ((u >> 16) & 1u);
  return (unsigned short)(r >> 16);
}

// ---------------------------------------------------------------------------
// Kernel 1: build conv weights (bf16, B-operand layout), fold self-connection
// into the center tap. Layout: Bwp[chunk8][grp45][och64][q4][j8]
//   k of MFMA = q*8+j  <->  (tap = grp*4+q, ich = chunk*8+j)
// ---------------------------------------------------------------------------
__global__ void build_w(const float* __restrict__ scw0, const float* __restrict__ scw1,
                        const float* __restrict__ tpw, unsigned short* __restrict__ Bwp) {
  int t = blockIdx.x;            // 0..179
  int tid = threadIdx.x;         // 256
  __shared__ float wsm[5][16][16];

  int dz = TAPS.dz[t], dy = TAPS.dy[t], dx = TAPS.dx[t];
  float fz = dz - 3.0f, fy = dy - 3.0f, fx = dx - 3.0f;
  float d2 = fz*fz + fy*fy + fx*fx;
  float r = sqrtf(d2);

  // radial embedding (linspace(0,3.5,10)[1:-1], step = 3.5/9)
  const float step = 3.5f / 9.0f;
  const float Cc = 1.14136f * 7.38905609893065f;   // 1.14136 * e^2
  float emb[8];
  for (int bb = 0; bb < 8; ++bb) {
    float diff = (r - step * (bb + 1)) / step;
    float t1 = diff + 1.0f, t2 = 1.0f - diff;
    float u1 = (t1 > 0.0f) ? expf(-1.0f / t1) : 0.0f;
    float u2 = (t2 > 0.0f) ? expf(-1.0f / t2) : 0.0f;
    emb[bb] = Cc * u1 * u2;
  }

  // per-path 16x16 matrices: w_p[u][o] = sum_b emb_b * tpw[b, (p*16+u)*16+o] / 343
  int u = tid >> 4, o = tid & 15;
  for (int p = 0; p < 5; ++p) {
    float acc = 0.0f;
    int nidx = (p * 16 + u) * 16 + o;
    for (int bb = 0; bb < 8; ++bb) acc += emb[bb] * tpw[bb * 1280 + nidx];
    wsm[p][u][o] = acc * (1.0f / 343.0f);
  }
  __syncthreads();

  float invr = (d2 > 0.0f) ? (1.7320508075688772f / r) : 0.0f;  // sqrt(3)/r
  float sh[3] = { fz * invr, fy * invr, fx * invr };

  bool center = (dz == 3 && dy == 3 && dx == 3);
  bool padt = (t >= NT_REAL);
  const float c1 = 0.17677669529663687f;   // sqrt(1/32)
  const float c2 = 0.10206207261596575f;   // c1/sqrt(3)
  const float c3 = 0.14433756729740643f;   // 0.25/sqrt(3)
  const float c4 = 0.14433756729740643f;
  const float c5 = 0.10206207261596575f;   // 0.25/sqrt(6)
  const float inv = 0.25f;                 // 1/sqrt(MUL)

  for (int e = tid; e < 4096; e += 256) {
    int ich = e & 63, och = e >> 6;
    float v = 0.0f;
    if (!padt) {
      if (och < 16) {
        if (ich < 16) {                               // scalar->scalar
          v = c1 * wsm[0][ich][och];
          if (center) v += inv * scw0[ich * 16 + och];
        } else {                                      // vector->scalar
          int q = ich - 16; int uu = q / 3, ii = q % 3;
          v = c2 * sh[ii] * wsm[1][uu][och];
        }
      } else {
        int qo = och - 16; int oo = qo / 3, kk = qo % 3;
        if (ich < 16) {                               // scalar->vector
          v = c3 * sh[kk] * wsm[2][ich][oo];
        } else {                                      // vector->vector
          int qi = ich - 16; int uu = qi / 3, ii = qi % 3;
          if (ii == kk) {
            v = c4 * wsm[3][uu][oo];
            if (center) v += inv * scw1[uu * 16 + oo];
          } else {
            int jj = 3 - ii - kk;
            float sgn = (((kk - ii + 3) % 3) == 2) ? 1.0f : -1.0f;
            v = c5 * sgn * sh[jj] * wsm[4][uu][oo];
          }
        }
      }
    }
    int chunk = ich >> 3, j = ich & 7, q = t & 3, grp = t >> 2;
    Bwp[(((size_t)(chunk * NGRP + grp) * 64 + och) * 4 + q) * 8 + j] = f2bf(v);
  }
}

// ---------------------------------------------------------------------------
// Kernel 2: x [2,64,40,40,40] fp32 -> zero-padded channel-last bf16
//           Xp [2][46][46][46][64]
// ---------------------------------------------------------------------------
__global__ void pad_cvt(const float* __restrict__ x, unsigned short* __restrict__ Xp) {
  int pos = blockIdx.x * 256 + threadIdx.x;
  const int P = 2 * 46 * 46 * 46;
  if (pos >= P) return;
  int xp = pos % 46; int t = pos / 46;
  int yp = t % 46;   t /= 46;
  int zp = t % 46;   int b = t / 46;
  int ix = xp - 3, iy = yp - 3, iz = zp - 3;
  bool inside = ((unsigned)ix < 40u) && ((unsigned)iy < 40u) && ((unsigned)iz < 40u);
  unsigned short* dst = Xp + (size_t)pos * 64;
  if (inside) {
    const float* src = x + (size_t)b * 64 * 64000 + (size_t)iz * 1600 + iy * 40 + ix;
    for (int g = 0; g < 8; ++g) {
      s16x8 v;
      for (int j = 0; j < 8; ++j)
        v[j] = (short)f2bf(src[(size_t)(g * 8 + j) * 64000]);
      *reinterpret_cast<s16x8*>(dst + g * 8) = v;
    }
  } else {
    s16x8 z{};
    for (int g = 0; g < 8; ++g) *reinterpret_cast<s16x8*>(dst + g * 8) = z;
  }
}

// ---------------------------------------------------------------------------
// Kernel 3: implicit-GEMM conv. Block = 256 thr (4 waves), tile = 256 output
// positions (4z x 8y x 8x) x 64 och. 8 ich-chunks x 45 tap-groups; per MFMA
// k=32 = 4 taps x 8 ich. LDS: halo 10x14x14x8ich (31.4KB, xor-swizzled 16B
// slots) + B group buffer (8 tap-groups = 32KB).
// ---------------------------------------------------------------------------
__global__ __launch_bounds__(256) void conv3d(
    const unsigned short* __restrict__ Xp,   // [2][46][46][46][64] bf16
    const unsigned short* __restrict__ Bwp,  // [8][45][64][4][8]   bf16
    float* __restrict__ out) {               // [2][64][40][40][40] fp32
  __shared__ unsigned short lds_mem[15680 + 16384];
  unsigned short* XH = lds_mem;              // 1960 positions x 16B
  unsigned short* BS = lds_mem + 15680;      // 8 grp x 64 och x 32 k

  int tid = threadIdx.x;
  int lane = tid & 63;
  int w = tid >> 6;          // wave 0..3
  int q = lane >> 4;         // quad: selects tap within group (A) / k-group (B)
  int n = lane & 15;         // A: m (position-in-tile);  B/D: n (och-in-tile)
  int m = n;

  int blk = blockIdx.x;      // 500 = 2 * 10 * 5 * 5
  int b  = blk / 250;
  int rr = blk % 250;
  int tz = rr / 25, ty = (rr / 5) % 5, tx = rr % 5;
  int z0 = tz * 4, y0 = ty * 8, x0 = tx * 8;

  // lane's position base in halo coords (m-tile a adds 28*a = 2 rows of y)
  int posA = w * 196 + (m >> 3) * 14 + (m & 7);

  const unsigned short* xsrc = Xp + (size_t)(((b * 46 + z0) * 46 + y0) * 46 + x0) * 64;

  f32x4 acc[4][4];
  #pragma unroll
  for (int a = 0; a < 4; ++a)
    #pragma unroll
    for (int nt = 0; nt < 4; ++nt) acc[a][nt] = f32x4{0.f, 0.f, 0.f, 0.f};

  for (int c = 0; c < 8; ++c) {            // ich chunk (8 channels)
    __syncthreads();                       // prev chunk/segment reads done
    // ---- stage halo chunk c (1960 positions x 16B), xor-swizzled slots ----
    for (int i = tid; i < 1960; i += 256) {
      int hx = i % 14; int t2 = i / 14; int hy = t2 % 14; int hz = t2 / 14;
      s16x8 v = *reinterpret_cast<const s16x8*>(
          xsrc + ((size_t)(hz * 46 + hy) * 46 + hx) * 64 + c * 8);
      int s = i << 4;
      int ad = s ^ (((s >> 7) & 7) << 4);
      *reinterpret_cast<s16x8*>(reinterpret_cast<char*>(XH) + ad) = v;
    }
    // ---- tap-group segments ----
    for (int g0 = 0; g0 < NGRP; g0 += 8) {
      int ng = (NGRP - g0 < 8) ? (NGRP - g0) : 8;
      if (g0 > 0) __syncthreads();         // prev segment's BS reads done
      const unsigned short* bsrc = Bwp + ((size_t)c * NGRP + g0) * 2048;
      for (int i = tid; i < ng * 256; i += 256)
        *reinterpret_cast<s16x8*>(BS + i * 8) =
            *reinterpret_cast<const s16x8*>(bsrc + i * 8);
      __syncthreads();                     // publish XH (first seg) + BS

      for (int gg = 0; gg < ng; ++gg) {
        int tb = (g0 + gg) * 4;
        int d0 = TAPS.dlin[tb + 0];
        int d1 = TAPS.dlin[tb + 1];
        int d2_ = TAPS.dlin[tb + 2];
        int d3 = TAPS.dlin[tb + 3];
        int dl = (q == 0) ? d0 : (q == 1) ? d1 : (q == 2) ? d2_ : d3;

        s16x8 afr[4];
        #pragma unroll
        for (int a = 0; a < 4; ++a) {
          int s = (posA + 28 * a + dl) << 4;
          int ad = s ^ (((s >> 7) & 7) << 4);
          afr[a] = *reinterpret_cast<const s16x8*>(
              reinterpret_cast<const char*>(XH) + ad);
        }
        const unsigned short* bp = BS + (size_t)gg * 2048 + (n * 32) + q * 8;
        s16x8 bfr[4];
        #pragma unroll
        for (int nt = 0; nt < 4; ++nt)
          bfr[nt] = *reinterpret_cast<const s16x8*>(bp + nt * 512);

        #pragma unroll
        for (int a = 0; a < 4; ++a)
          #pragma unroll
          for (int nt = 0; nt < 4; ++nt)
            acc[a][nt] = __builtin_amdgcn_mfma_f32_16x16x32_bf16(
                afr[a], bfr[nt], acc[a][nt], 0, 0, 0);
      }
    }
  }

  // ---- epilogue: D lane map col=lane&15 (och), row=q*4+reg (position) ----
  // row -> px = (q&1)*4 + reg, py += q>>1 ; m-tile a -> py += a*2 ; pz = w
  #pragma unroll
  for (int nt = 0; nt < 4; ++nt) {
    size_t cb = (size_t)(b * 64 + nt * 16 + n) * 64000
              + (size_t)(z0 + w) * 1600
              + (size_t)(x0 + (q & 1) * 4);
    #pragma unroll
    for (int a = 0; a < 4; ++a) {
      float* dst = out + cb + (size_t)(y0 + a * 2 + (q >> 1)) * 40;
      *reinterpret_cast<f32x4*>(dst) = acc[a][nt];
    }
  }
}

// ---------------------------------------------------------------------------
extern "C" void kernel_launch(void* const* d_in, const int* in_sizes, int n_in,
                              void* d_out, int out_size, void* d_ws, size_t ws_size,
                              hipStream_t stream) {
  const float* x    = (const float*)d_in[0];  // [2,64,40,40,40]
  const float* scw0 = (const float*)d_in[1];  // [16,16]
  const float* scw1 = (const float*)d_in[2];  // [16,16]
  const float* tpw  = (const float*)d_in[3];  // [8,1280]
  float* out = (float*)d_out;

  unsigned short* Xp  = (unsigned short*)d_ws;                 // 24,918,016 B
  unsigned short* Bwp = Xp + (size_t)2 * 46 * 46 * 46 * 64;    // 1,474,560 B

  build_w<<<NT_PAD, 256, 0, stream>>>(scw0, scw1, tpw, Bwp);
  pad_cvt<<<(2 * 46 * 46 * 46 + 255) / 256, 256, 0, stream>>>(x, Xp);
  conv3d<<<500, 256, 0, stream>>>(Xp, Bwp, out);
}

// Round 2
// 289.100 us; speedup vs baseline: 1.4112x; 1.4112x over previous
//
#include <hip/hip_runtime.h>
#include <stdint.h>

// ---------------------------------------------------------------------------
// Equivariant conv = self-connection (folded into center tap) + sparse-tap
// implicit-GEMM bf16 MFMA conv. R2: M=512 tiles, async global_load_lds
// double-buffered pipeline, conflict-free B LDS layout.
// ---------------------------------------------------------------------------

#define NT_REAL 179   // taps with d^2 <= 12 (radial shells vanish beyond r=3.5)
#define NT_PAD  180
#define NGRP    45    // NT_PAD/4 taps per MFMA k-step

typedef short s16x8 __attribute__((ext_vector_type(8)));
typedef float f32x4 __attribute__((ext_vector_type(4)));

struct Taps {
  int n;
  short dl16[NT_PAD];                       // (dz*14+dy)*16 + dx (halo slot offset)
  unsigned char dz[NT_PAD], dy[NT_PAD], dx[NT_PAD];
};
constexpr Taps mk_taps() {
  Taps t{};
  t.n = 0;
  for (int a = 0; a < 7; ++a)
    for (int b = 0; b < 7; ++b)
      for (int c = 0; c < 7; ++c) {
        int d2 = (a-3)*(a-3) + (b-3)*(b-3) + (c-3)*(c-3);
        if (d2 <= 12) {
          t.dz[t.n] = (unsigned char)a; t.dy[t.n] = (unsigned char)b;
          t.dx[t.n] = (unsigned char)c;
          t.dl16[t.n] = (short)((a*14 + b)*16 + c);
          ++t.n;
        }
      }
  for (int i = t.n; i < NT_PAD; ++i) {      // pad tap: zero weights, valid addr
    t.dz[i] = 3; t.dy[i] = 3; t.dx[i] = 3; t.dl16[i] = t.dl16[0];
  }
  return t;
}
__device__ constexpr Taps TAPS = mk_taps();
static_assert(mk_taps().n == NT_REAL, "tap count");

static __device__ inline unsigned short f2bf(float f) {   // RNE fp32->bf16
  unsigned int u = __float_as_uint(f);
  unsigned int r = u + 0x7FFFu + ((u >> 16) & 1u);
  return (unsigned short)(r >> 16);
}

__device__ __forceinline__ void gl_lds16(const void* g, void* s) {
  // async 16B/lane global->LDS; LDS dest = wave-uniform base + lane*16
  __builtin_amdgcn_global_load_lds(
      (const __attribute__((address_space(1))) void*)g,
      (__attribute__((address_space(3))) void*)s, 16, 0, 0);
}

// ---------------------------------------------------------------------------
// Kernel 1: build conv weights (bf16, B-operand layout), fold self-connection
// into center tap. Layout: Bwp[chunk8][grp45][nt4][q4][n16][j8]
//   MFMA k = q*8+j <-> (tap = grp*4+q, ich = chunk*8+j); och = nt*16+n.
//   Fragment for lane (q,n) sits at byte (q*16+n)*16 -> conflict-free reads.
// ---------------------------------------------------------------------------
__global__ void build_w(const float* __restrict__ scw0, const float* __restrict__ scw1,
                        const float* __restrict__ tpw, unsigned short* __restrict__ Bwp) {
  int t = blockIdx.x;            // 0..179
  int tid = threadIdx.x;         // 256
  __shared__ float wsm[5][16][16];

  int dz = TAPS.dz[t], dy = TAPS.dy[t], dx = TAPS.dx[t];
  float fz = dz - 3.0f, fy = dy - 3.0f, fx = dx - 3.0f;
  float d2 = fz*fz + fy*fy + fx*fx;
  float r = sqrtf(d2);

  const float step = 3.5f / 9.0f;
  const float Cc = 1.14136f * 7.38905609893065f;   // 1.14136 * e^2
  float emb[8];
  for (int bb = 0; bb < 8; ++bb) {
    float diff = (r - step * (bb + 1)) / step;
    float t1 = diff + 1.0f, t2 = 1.0f - diff;
    float u1 = (t1 > 0.0f) ? expf(-1.0f / t1) : 0.0f;
    float u2 = (t2 > 0.0f) ? expf(-1.0f / t2) : 0.0f;
    emb[bb] = Cc * u1 * u2;
  }

  int u = tid >> 4, o = tid & 15;
  for (int p = 0; p < 5; ++p) {
    float acc = 0.0f;
    int nidx = (p * 16 + u) * 16 + o;
    for (int bb = 0; bb < 8; ++bb) acc += emb[bb] * tpw[bb * 1280 + nidx];
    wsm[p][u][o] = acc * (1.0f / 343.0f);
  }
  __syncthreads();

  float invr = (d2 > 0.0f) ? (1.7320508075688772f / r) : 0.0f;  // sqrt(3)/r
  float sh[3] = { fz * invr, fy * invr, fx * invr };

  bool center = (dz == 3 && dy == 3 && dx == 3);
  bool padt = (t >= NT_REAL);
  const float c1 = 0.17677669529663687f;   // sqrt(1/32)
  const float c2 = 0.10206207261596575f;   // c1/sqrt(3)
  const float c3 = 0.14433756729740643f;   // 0.25/sqrt(3)
  const float c4 = 0.14433756729740643f;
  const float c5 = 0.10206207261596575f;   // 0.25/sqrt(6)
  const float inv = 0.25f;                 // 1/sqrt(MUL)

  for (int e = tid; e < 4096; e += 256) {
    int ich = e & 63, och = e >> 6;
    float v = 0.0f;
    if (!padt) {
      if (och < 16) {
        if (ich < 16) {                               // scalar->scalar
          v = c1 * wsm[0][ich][och];
          if (center) v += inv * scw0[ich * 16 + och];
        } else {                                      // vector->scalar
          int qq = ich - 16; int uu = qq / 3, ii = qq % 3;
          v = c2 * sh[ii] * wsm[1][uu][och];
        }
      } else {
        int qo = och - 16; int oo = qo / 3, kk = qo % 3;
        if (ich < 16) {                               // scalar->vector
          v = c3 * sh[kk] * wsm[2][ich][oo];
        } else {                                      // vector->vector
          int qi = ich - 16; int uu = qi / 3, ii = qi % 3;
          if (ii == kk) {
            v = c4 * wsm[3][uu][oo];
            if (center) v += inv * scw1[uu * 16 + oo];
          } else {
            int jj = 3 - ii - kk;
            float sgn = (((kk - ii + 3) % 3) == 2) ? 1.0f : -1.0f;
            v = c5 * sgn * sh[jj] * wsm[4][uu][oo];
          }
        }
      }
    }
    int chunk = ich >> 3, j = ich & 7, q = t & 3, grp = t >> 2;
    int nt = och >> 4, n = och & 15;
    size_t idx = (((((size_t)chunk * NGRP + grp) * 4 + nt) * 4 + q) * 16 + n) * 8 + j;
    Bwp[idx] = f2bf(v);
  }
}

// ---------------------------------------------------------------------------
// Kernel 2: x [2,64,40,40,40] fp32 -> zero-padded channel-last bf16
//           Xp [2][46][46][46][64]. One block per (b,zp,yp) row, LDS transpose,
//           coalesced reads (x-contig) and writes (row-contig 16B/lane).
// ---------------------------------------------------------------------------
__global__ void pad_cvt(const float* __restrict__ x, unsigned short* __restrict__ Xp) {
  __shared__ float buf[46 * 65];
  int blk = blockIdx.x;             // (b*46 + zp)*46 + yp
  int yp = blk % 46; int t = blk / 46; int zp = t % 46; int b = t / 46;
  int iz = zp - 3, iy = yp - 3;
  bool rowin = ((unsigned)iz < 40u) && ((unsigned)iy < 40u);
  int tid = threadIdx.x;
  if (rowin) {
    const float* src = x + (size_t)b * 4096000 + (size_t)iz * 1600 + (size_t)iy * 40;
    for (int e = tid; e < 64 * 46; e += 256) {
      int ch = e / 46, xp = e - ch * 46;
      int ix = xp - 3;
      float v = ((unsigned)ix < 40u) ? src[(size_t)ch * 64000 + ix] : 0.0f;
      buf[xp * 65 + ch] = v;
    }
  }
  __syncthreads();
  for (int f = tid; f < 46 * 8; f += 256) {
    int xp = f >> 3, g = f & 7;
    s16x8 v = s16x8{0, 0, 0, 0, 0, 0, 0, 0};
    if (rowin) {
      #pragma unroll
      for (int j = 0; j < 8; ++j) v[j] = (short)f2bf(buf[xp * 65 + g * 8 + j]);
    }
    *reinterpret_cast<s16x8*>(Xp + ((size_t)blk * 46 + xp) * 64 + g * 8) = v;
  }
}

// ---------------------------------------------------------------------------
// Kernel 3: implicit-GEMM conv. Block = 512 thr (8 waves), tile = 512 output
// positions (8z x 8y x 8x) x 64 och. Wave w = z-plane w: 4 m-tiles x 4 n-tiles.
// Pipeline: 72 steps (8 ich-chunks x 9 B-segments of 5 tap-groups); B and halo
// double-buffered, staged with async global_load_lds issued right after each
// barrier so every drain is covered by a full compute step.
// LDS: halo 2 x (14*14*16 slots * 16B = 50176) + B 2 x 20480 = 141312 B.
// ---------------------------------------------------------------------------
__global__ __launch_bounds__(512) void conv3d(
    const unsigned short* __restrict__ Xp,   // [2][46][46][46][64] bf16
    const unsigned short* __restrict__ Bwp,  // [8][45][4][4][16][8] bf16
    float* __restrict__ out) {               // [2][64][40][40][40] fp32
  __shared__ __align__(16) unsigned char smem[141312];
  unsigned char* XH = smem;                  // 2 x 50176
  unsigned char* BB = smem + 100352;         // 2 x 20480

  int blk = blockIdx.x;                      // 256 blocks, 6 dummies
  int p = ((blk & 7) << 5) | (blk >> 3);     // XCD-contiguous tile ranges
  if (p >= 250) return;
  int b = p / 125; int rem = p - b * 125;
  int tz = rem / 25, ty = (rem / 5) % 5, tx = rem % 5;

  int tid = threadIdx.x;
  int lane = tid & 63;
  int w = tid >> 6;                          // wave 0..7 -> z-plane
  int q = lane >> 4, n = lane & 15;

  const unsigned char* xg = (const unsigned char*)Xp
      + (size_t)(((b * 46 + tz * 8) * 46 + ty * 8) * 46 + tx * 8) * 128;

  // A fragment base slot: z-plane w (stride 224 slots), y_rel = n>>3, x = n&7
  int abase = w * 224 + ((n >> 3) << 4) + (n & 7);

  f32x4 acc[4][4];
  #pragma unroll
  for (int a = 0; a < 4; ++a)
    #pragma unroll
    for (int nt = 0; nt < 4; ++nt) acc[a][nt] = f32x4{0.f, 0.f, 0.f, 0.f};

  // ---- async staging (per-wave slices; each instr = 64 lanes x 16B = 1KB) --
  auto stageB = [&](int c, int s, unsigned char* dst) {
    const unsigned char* bg = (const unsigned char*)Bwp
        + ((size_t)c * NGRP + s * 5) * 4096;           // 5 grps x 4096 B
    for (int k = w; k < 20; k += 8)
      gl_lds16(bg + (k << 10) + lane * 16, dst + (k << 10));
  };
  auto stageH = [&](int c, unsigned char* dst) {
    for (int k = w; k < 49; k += 8) {                  // 3136 slots / 64
      int sl = (k << 6) + lane;
      int hx = sl & 15; hx = hx > 13 ? 13 : hx;        // phantom x-slots clamp
      int r = sl >> 4;                                 // hz*14+hy, < 196
      int hz = (r * 2341) >> 15;                       // r/14
      int hy = r - hz * 14;
      gl_lds16(xg + ((size_t)((hz * 46 + hy) * 46 + hx)) * 128 + c * 16,
               dst + (k << 10));
    }
  };

  stageB(0, 0, BB);
  stageH(0, XH);

  int t = 0;
  for (int c = 0; c < 8; ++c) {
    const unsigned char* XHc = XH + (c & 1) * 50176;
    for (int s = 0; s < 9; ++s, ++t) {
      __syncthreads();   // drains own vmcnt: step-t buffers are ready
      if (t + 1 < 72) {
        int cn = (s == 8) ? c + 1 : c;
        int sn = (s == 8) ? 0 : s + 1;
        stageB(cn, sn, BB + ((t + 1) & 1) * 20480);    // in flight during compute
      }
      if (s == 0 && c < 7) stageH(c + 1, XH + ((c + 1) & 1) * 50176);

      const unsigned char* BSc = BB + (t & 1) * 20480 + (size_t)lane * 16;
      #pragma unroll
      for (int gg = 0; gg < 5; ++gg) {
        int tb = (s * 5 + gg) << 2;
        int d0 = TAPS.dl16[tb], d1 = TAPS.dl16[tb + 1];
        int d2_ = TAPS.dl16[tb + 2], d3 = TAPS.dl16[tb + 3];
        int dl = (q == 0) ? d0 : (q == 1) ? d1 : (q == 2) ? d2_ : d3;
        const unsigned char* ab = XHc + ((size_t)(abase + dl) << 4);
        s16x8 a0 = *(const s16x8*)(ab);
        s16x8 a1 = *(const s16x8*)(ab + 512);          // +2 y-rows (32 slots)
        s16x8 a2 = *(const s16x8*)(ab + 1024);
        s16x8 a3 = *(const s16x8*)(ab + 1536);
        const unsigned char* bp = BSc + (gg << 12);
        s16x8 b0 = *(const s16x8*)(bp);
        s16x8 b1 = *(const s16x8*)(bp + 1024);
        s16x8 b2 = *(const s16x8*)(bp + 2048);
        s16x8 b3 = *(const s16x8*)(bp + 3072);
        acc[0][0] = __builtin_amdgcn_mfma_f32_16x16x32_bf16(a0, b0, acc[0][0], 0, 0, 0);
        acc[0][1] = __builtin_amdgcn_mfma_f32_16x16x32_bf16(a0, b1, acc[0][1], 0, 0, 0);
        acc[0][2] = __builtin_amdgcn_mfma_f32_16x16x32_bf16(a0, b2, acc[0][2], 0, 0, 0);
        acc[0][3] = __builtin_amdgcn_mfma_f32_16x16x32_bf16(a0, b3, acc[0][3], 0, 0, 0);
        acc[1][0] = __builtin_amdgcn_mfma_f32_16x16x32_bf16(a1, b0, acc[1][0], 0, 0, 0);
        acc[1][1] = __builtin_amdgcn_mfma_f32_16x16x32_bf16(a1, b1, acc[1][1], 0, 0, 0);
        acc[1][2] = __builtin_amdgcn_mfma_f32_16x16x32_bf16(a1, b2, acc[1][2], 0, 0, 0);
        acc[1][3] = __builtin_amdgcn_mfma_f32_16x16x32_bf16(a1, b3, acc[1][3], 0, 0, 0);
        acc[2][0] = __builtin_amdgcn_mfma_f32_16x16x32_bf16(a2, b0, acc[2][0], 0, 0, 0);
        acc[2][1] = __builtin_amdgcn_mfma_f32_16x16x32_bf16(a2, b1, acc[2][1], 0, 0, 0);
        acc[2][2] = __builtin_amdgcn_mfma_f32_16x16x32_bf16(a2, b2, acc[2][2], 0, 0, 0);
        acc[2][3] = __builtin_amdgcn_mfma_f32_16x16x32_bf16(a2, b3, acc[2][3], 0, 0, 0);
        acc[3][0] = __builtin_amdgcn_mfma_f32_16x16x32_bf16(a3, b0, acc[3][0], 0, 0, 0);
        acc[3][1] = __builtin_amdgcn_mfma_f32_16x16x32_bf16(a3, b1, acc[3][1], 0, 0, 0);
        acc[3][2] = __builtin_amdgcn_mfma_f32_16x16x32_bf16(a3, b2, acc[3][2], 0, 0, 0);
        acc[3][3] = __builtin_amdgcn_mfma_f32_16x16x32_bf16(a3, b3, acc[3][3], 0, 0, 0);
      }
    }
  }

  // ---- epilogue: D lane map col=lane&15 (och), row=q*4+reg (position) ------
  #pragma unroll
  for (int nt = 0; nt < 4; ++nt) {
    size_t cb = (size_t)(b * 64 + nt * 16 + n) * 64000
              + (size_t)(tz * 8 + w) * 1600
              + (size_t)(tx * 8 + (q & 1) * 4);
    #pragma unroll
    for (int a = 0; a < 4; ++a) {
      float* dst = out + cb + (size_t)(ty * 8 + a * 2 + (q >> 1)) * 40;
      *reinterpret_cast<f32x4*>(dst) = acc[a][nt];
    }
  }
}

// ---------------------------------------------------------------------------
extern "C" void kernel_launch(void* const* d_in, const int* in_sizes, int n_in,
                              void* d_out, int out_size, void* d_ws, size_t ws_size,
                              hipStream_t stream) {
  const float* x    = (const float*)d_in[0];  // [2,64,40,40,40]
  const float* scw0 = (const float*)d_in[1];  // [16,16]
  const float* scw1 = (const float*)d_in[2];  // [16,16]
  const float* tpw  = (const float*)d_in[3];  // [8,1280]
  float* out = (float*)d_out;

  unsigned short* Xp  = (unsigned short*)d_ws;                 // 24,918,016 B
  unsigned short* Bwp = Xp + (size_t)2 * 46 * 46 * 46 * 64;    // 1,474,560 B

  build_w<<<NT_PAD, 256, 0, stream>>>(scw0, scw1, tpw, Bwp);
  pad_cvt<<<2 * 46 * 46, 256, 0, stream>>>(x, Xp);
  conv3d<<<256, 512, 0, stream>>>(Xp, Bwp, out);
}